// Round 1
// baseline (286.014 us; speedup 1.0000x reference)
//
#include <hip/hip_runtime.h>

// RoIMaskAlignAvg: features (B=2, C=256, H=200, W=272) fp32, rois (N=256,5)
// -> out (N, C, 14, 14) fp32.
//
// Restructured vs previous version:
//  - ONE sample row per wave-pass => y-geometry (sy, yl, yh, wy*) is
//    wave-uniform: row offsets go to SGPR via readfirstlane, loads become
//    saddr+voffset with the per-lane voffset hoisted (no per-row vector
//    address math).
//  - Lane halves hold 2 CHANNELS (not 2 rows); two channel-pairs per wave
//    => 4 channels/wave, 16/block, y-geometry amortized 4x.
//  - 4x4-stride-2 pooling done in registers: vertical pair-sums + shfl_xor(1)
//    + shfl_down(2) horizontal pairing; out(ah) = (S_ah + S_{ah+1})/16.
//    No LDS tiles, no __syncthreads, no bank conflicts.

#define AH_  14
#define AW_  14
#define C_   256
#define H_   200
#define W_   272
#define HW_  (H_ * W_)
#define CPW  4                 // channels per wave (2 lane-halves x 2 pairs)
#define CPB  (4 * CPW)         // 16 channels per block (4 waves)
#define NPAIR 15               // 30 sample rows = 15 vertical pairs

__global__ __launch_bounds__(256)
void roi_mask_align_avg_kernel(const float* __restrict__ feat,
                               const float* __restrict__ rois,
                               float* __restrict__ out) {
    const int p    = blockIdx.x;
    const int n    = p >> 4;            // roi index
    const int cg   = p & 15;            // channel group (16 ch each)
    const int tid  = threadIdx.x;
    const int wave = tid >> 6;
    const int lane = tid & 63;
    const int half = lane >> 5;         // which channel of the pair
    const int ix   = lane & 31;         // sample-x index (0..29 used)

    // --- per-roi geometry (block-uniform; fp op order preserved) ---
    const float r0f = rois[n * 5 + 0];
    const float x1s = rois[n * 5 + 1] * 0.25f;
    const float y1s = rois[n * 5 + 2] * 0.25f;
    const float x2s = rois[n * 5 + 3] * 0.25f;
    const float y2s = rois[n * 5 + 4] * 0.25f;
    const int   b   = (int)r0f;

    const float cx = 0.5f * (x1s + x2s), cy = 0.5f * (y1s + y2s);
    const float hw = 0.5f * (x2s - x1s), hh = 0.5f * (y2s - y1s);
    const float x1 = cx - hw, x2 = cx + hw;
    const float y1 = cy - hh, y2 = cy + hh;
    const float roi_w = fmaxf(x2 - x1, 1.0f);
    const float roi_h = fmaxf(y2 - y1, 1.0f);
    const float sub_w = roi_w * (1.0f / 15.0f) * 0.5f;   // bin_w / r
    const float sub_h = roi_h * (1.0f / 15.0f) * 0.5f;

    // --- x-direction sample metadata: per lane, computed once ---
    const float sx  = x1 + ((float)ix + 0.5f) * sub_w;
    const bool  vx_ = (sx > -1.0f) && (sx < (float)W_) && (ix < 30);
    const float ccx = fminf(fmaxf(sx, 0.0f), (float)(W_ - 1));
    const float lox = floorf(ccx);
    const int   xl  = (int)lox;
    const int   xh  = min(xl + 1, W_ - 1);
    const float fx  = ccx - lox;
    const float vmx = vx_ ? 1.0f : 0.0f;
    const float wx0 = (1.0f - fx) * vmx;
    const float wx1 = fx * vmx;

    // --- channel bases (uniform per wave) + hoisted per-lane offsets ---
    const int cA = cg * CPB + wave * CPW;       // first channel of pair A
    const float* __restrict__ bpA = feat + ((size_t)b * C_ + cA) * (size_t)HW_;
    const float* __restrict__ bpB = bpA + 2 * HW_;
    const int vx0 = half * HW_ + xl;            // constant element offsets
    const int vx1 = half * HW_ + xh;

    float* __restrict__ opA = out + ((size_t)n * C_ + cA) * (AH_ * AW_);
    const int  aw   = ix >> 1;
    const int  so   = half * (AH_ * AW_) + aw;  // constant part of store off
    const bool emit = ((lane & 1) == 0) && (aw < AW_);

    float prevSA = 0.0f, prevSB = 0.0f;

    #pragma unroll
    for (int k = 0; k < NPAIR; ++k) {
        float PA = 0.0f, PB = 0.0f;
        #pragma unroll
        for (int r = 0; r < 2; ++r) {
            const int iy = 2 * k + r;
            // y geometry: wave-uniform
            const float sy  = y1 + ((float)iy + 0.5f) * sub_h;
            const bool  vy_ = (sy > -1.0f) && (sy < (float)H_);
            const float ccy = fminf(fmaxf(sy, 0.0f), (float)(H_ - 1));
            const float loy = floorf(ccy);
            const int   yl  = (int)loy;
            const int   yh  = min(yl + 1, H_ - 1);
            const float fy  = ccy - loy;
            const float vmy = vy_ ? 1.0f : 0.0f;
            const float wy0 = (1.0f - fy) * vmy;
            const float wy1 = fy * vmy;

            // force row offsets scalar -> saddr-form loads
            const int ro0 = __builtin_amdgcn_readfirstlane(yl * W_);
            const int ro1 = __builtin_amdgcn_readfirstlane(yh * W_);
            const float* __restrict__ rA0 = bpA + ro0;
            const float* __restrict__ rA1 = bpA + ro1;
            const float* __restrict__ rB0 = bpB + ro0;
            const float* __restrict__ rB1 = bpB + ro1;

            const float w00 = wy0 * wx0, w01 = wy0 * wx1;
            const float w10 = wy1 * wx0, w11 = wy1 * wx1;

            const float a00 = rA0[vx0], a01 = rA0[vx1];
            const float a10 = rA1[vx0], a11 = rA1[vx1];
            const float c00 = rB0[vx0], c01 = rB0[vx1];
            const float c10 = rB1[vx0], c11 = rB1[vx1];

            const float vA = a00 * w00 + a01 * w01 + a10 * w10 + a11 * w11;
            const float vB = c00 * w00 + c01 * w01 + c10 * w10 + c11 * w11;
            PA += vA;
            PB += vB;
        }
        // horizontal pooling in registers:
        // t[2j],t[2j+1] = P[2j]+P[2j+1] = Q_j ; u[2j] = Q_j + Q_{j+1} = S[aw=j]
        const float tA = PA + __shfl_xor(PA, 1, 64);
        const float uA = tA + __shfl_down(tA, 2, 64);
        const float tB = PB + __shfl_xor(PB, 1, 64);
        const float uB = tB + __shfl_down(tB, 2, 64);
        if (k > 0 && emit) {
            // out(ah=k-1, aw) = (S_{k-1} + S_k) / 16 ; B-pair at +2 channels
            opA[so + (k - 1) * AW_]                    = (prevSA + uA) * 0.0625f;
            opA[so + (k - 1) * AW_ + 2 * (AH_ * AW_)]  = (prevSB + uB) * 0.0625f;
        }
        prevSA = uA;
        prevSB = uB;
    }
}

extern "C" void kernel_launch(void* const* d_in, const int* in_sizes, int n_in,
                              void* d_out, int out_size, void* d_ws, size_t ws_size,
                              hipStream_t stream) {
    const float* feat = (const float*)d_in[0];
    const float* rois = (const float*)d_in[1];
    float* out = (float*)d_out;
    const int grid = 256 * (C_ / CPB);   // 4096 blocks, 256 threads
    roi_mask_align_avg_kernel<<<grid, 256, 0, stream>>>(feat, rois, out);
}

// Round 2
// 267.387 us; speedup vs baseline: 1.0697x; 1.0697x over previous
//
#include <hip/hip_runtime.h>

// RoIMaskAlignAvg: features (B=2, C=256, H=200, W=272) fp32, rois (N=256,5)
// -> out (N, C, 14, 14) fp32.
//
// v2 = v1's register-pooling structure + v0's proven XCD/L2 swizzle:
//  - XCD-aware swizzle p = xcd + 8*(n + 256*cgi): each XCD streams a fixed
//    4-channel slice (2 batches x 4ch x 217.6KB = 1.74 MB, L2-resident)
//    over all 256 rois. This held FETCH_SIZE at 43 MB in v0; v1's mapping
//    blew it up to 255 MB.
//  - ONE sample row per wave-pass: y-geometry wave-uniform, row offsets
//    readfirstlane'd to SGPR, per-lane voffset (half*HW + xl) hoisted.
//  - Lane halves hold 2 channels; 2 waves/block -> 4 channels/block (CPB=4).
//  - 4x4-stride-2 pooling in registers via shfl_xor(1)+shfl_down(2).
//  - Output staged in 3.1 KB LDS (same-wave only, no barrier) and written
//    as one contiguous 392-float stream per wave (coalesced; v1's scattered
//    row stores amplified WRITE_SIZE 50->68.6 MB).

#define AH_  14
#define AW_  14
#define C_   256
#define H_   200
#define W_   272
#define HW_  (H_ * W_)
#define CPW  2                 // channels per wave (2 lane-halves)
#define CPB  4                 // channels per block (2 waves)
#define NPAIR 15               // 30 sample rows = 15 vertical pairs

__global__ __launch_bounds__(128, 8)
void roi_mask_align_avg_kernel(const float* __restrict__ feat,
                               const float* __restrict__ rois,
                               float* __restrict__ out) {
    __shared__ float Ls[2][CPW * AH_ * AW_];   // 2 waves x 392 floats = 3.1 KB

    // --- XCD-aware swizzle (identical to the 137us v0 kernel) ---
    // physical p = xcd + 8*(n + 256*cgi);  cg = 8*cgi + xcd
    const int p   = blockIdx.x;
    const int xcd = p & 7;
    const int q   = p >> 3;
    const int n   = q & 255;           // roi index (advances fastest)
    const int cgi = q >> 8;            // 0..7
    const int cg  = cgi * 8 + xcd;     // 0..63
    const int c0  = cg * CPB;

    const int tid  = threadIdx.x;
    const int wave = tid >> 6;
    const int lane = tid & 63;
    const int half = lane >> 5;        // which channel of the wave's pair
    const int ix   = lane & 31;        // sample-x index (0..29 used)

    // --- per-roi geometry (block-uniform; fp op order preserved) ---
    const float r0f = rois[n * 5 + 0];
    const float x1s = rois[n * 5 + 1] * 0.25f;
    const float y1s = rois[n * 5 + 2] * 0.25f;
    const float x2s = rois[n * 5 + 3] * 0.25f;
    const float y2s = rois[n * 5 + 4] * 0.25f;
    const int   b   = (int)r0f;

    const float cx = 0.5f * (x1s + x2s), cy = 0.5f * (y1s + y2s);
    const float hw = 0.5f * (x2s - x1s), hh = 0.5f * (y2s - y1s);
    const float x1 = cx - hw, x2 = cx + hw;
    const float y1 = cy - hh, y2 = cy + hh;
    const float roi_w = fmaxf(x2 - x1, 1.0f);
    const float roi_h = fmaxf(y2 - y1, 1.0f);
    const float sub_w = roi_w * (1.0f / 15.0f) * 0.5f;   // bin_w / r
    const float sub_h = roi_h * (1.0f / 15.0f) * 0.5f;

    // --- x-direction sample metadata: per lane, computed once ---
    const float sx  = x1 + ((float)ix + 0.5f) * sub_w;
    const bool  vx_ = (sx > -1.0f) && (sx < (float)W_) && (ix < 30);
    const float ccx = fminf(fmaxf(sx, 0.0f), (float)(W_ - 1));
    const float lox = floorf(ccx);
    const int   xl  = (int)lox;
    const int   xh  = min(xl + 1, W_ - 1);
    const float fx  = ccx - lox;
    const float vmx = vx_ ? 1.0f : 0.0f;
    const float wx0 = (1.0f - fx) * vmx;
    const float wx1 = fx * vmx;

    // --- channel base (uniform per wave) + hoisted per-lane offsets ---
    const int cW = c0 + wave * CPW;             // first channel of this wave
    const float* __restrict__ bp = feat + ((size_t)b * C_ + cW) * (size_t)HW_;
    const int vx0 = half * HW_ + xl;            // constant element offsets
    const int vx1 = half * HW_ + xh;

    const int  aw   = ix >> 1;
    const int  so   = half * (AH_ * AW_) + aw;  // constant part of LDS offset
    const bool emit = ((lane & 1) == 0) && (aw < AW_);
    float* __restrict__ Lw = Ls[wave];

    float prevS = 0.0f;

    #pragma unroll
    for (int k = 0; k < NPAIR; ++k) {
        float P = 0.0f;
        #pragma unroll
        for (int r = 0; r < 2; ++r) {
            const int iy = 2 * k + r;
            // y geometry: wave-uniform
            const float sy  = y1 + ((float)iy + 0.5f) * sub_h;
            const bool  vy_ = (sy > -1.0f) && (sy < (float)H_);
            const float ccy = fminf(fmaxf(sy, 0.0f), (float)(H_ - 1));
            const float loy = floorf(ccy);
            const int   yl  = (int)loy;
            const int   yh  = min(yl + 1, H_ - 1);
            const float fy  = ccy - loy;
            const float vmy = vy_ ? 1.0f : 0.0f;
            const float wy0 = (1.0f - fy) * vmy;
            const float wy1 = fy * vmy;

            // force row offsets scalar -> saddr-form loads
            const int ro0 = __builtin_amdgcn_readfirstlane(yl * W_);
            const int ro1 = __builtin_amdgcn_readfirstlane(yh * W_);
            const float* __restrict__ r0p = bp + ro0;
            const float* __restrict__ r1p = bp + ro1;

            const float w00 = wy0 * wx0, w01 = wy0 * wx1;
            const float w10 = wy1 * wx0, w11 = wy1 * wx1;

            P += r0p[vx0] * w00 + r0p[vx1] * w01
               + r1p[vx0] * w10 + r1p[vx1] * w11;
        }
        // horizontal pooling in registers:
        // t[2j] = P[2j]+P[2j+1] = Q_j ; u[2j] = Q_j + Q_{j+1} = S[aw=j]
        const float t = P + __shfl_xor(P, 1, 64);
        const float u = t + __shfl_down(t, 2, 64);
        if (k > 0 && emit) {
            Lw[so + (k - 1) * AW_] = (prevS + u) * 0.0625f;
        }
        prevS = u;
    }

    // --- coalesced writeback: 392 contiguous floats per wave ---
    // out channel stride = 196 floats; the wave's 2 channels are adjacent.
    float* __restrict__ op = out + ((size_t)n * C_ + cW) * (AH_ * AW_);
    for (int o = lane; o < CPW * AH_ * AW_; o += 64) {
        op[o] = Lw[o];
    }
}

extern "C" void kernel_launch(void* const* d_in, const int* in_sizes, int n_in,
                              void* d_out, int out_size, void* d_ws, size_t ws_size,
                              hipStream_t stream) {
    const float* feat = (const float*)d_in[0];
    const float* rois = (const float*)d_in[1];
    float* out = (float*)d_out;
    const int grid = 256 * (C_ / CPB);   // 16384 blocks, 128 threads
    roi_mask_align_avg_kernel<<<grid, 128, 0, stream>>>(feat, rois, out);
}

// Round 3
// 245.453 us; speedup vs baseline: 1.1653x; 1.0894x over previous
//
#include <hip/hip_runtime.h>

// RoIMaskAlignAvg: features (B=2, C=256, H=200, W=272) fp32, rois (N=256,5)
// -> out (N, C, 14, 14) fp32.
//
// v3: attack the VMEM-instruction wall (both v0@137us and v2@142us issue
// 2 global_load_dword per channel per sample-row = 3.93M wave-loads;
// at ~16cyc/wave64-load that's ~100us of VMEM issue -- the shared floor).
//  - ROW REUSE: sub_h = roi_h/30 averages ~1.4, so consecutive sample rows
//    usually share a feature row. Keep the 4 corner values per channel-pair
//    in registers; per sample row branch on SCALAR yl (wave-uniform,
//    s_cbranch) into {reuse both rows / shift + load 1 row / load 2 rows}.
//    E[new rows] = E[min(sub_h,2)] ~ 1.36 vs 2  =>  -32% VMEM instrs.
//  - CPW=4: lane-half = 2 channels, 2 register channel-pairs (A,B).
//    30 sample rows split across 2 waves (wave0: iy0..15 -> out rows 0..6,
//    wave1: iy14..29 -> rows 7..13; pair 7 computed by both). CPB stays 4
//    => proven 1.74MB/XCD L2 slice (FETCH 45MB) untouched.
//  - Wave-uniform y-geometry + readfirstlane saddr loads, register shuffle
//    pooling, per-wave LDS output staging + coalesced writeback (all kept).

#define AH_  14
#define AW_  14
#define C_   256
#define H_   200
#define W_   272
#define HW_  (H_ * W_)
#define CPB  4                 // channels per block

__global__ __launch_bounds__(128, 8)
void roi_mask_align_avg_kernel(const float* __restrict__ feat,
                               const float* __restrict__ rois,
                               float* __restrict__ out) {
    __shared__ float Ls[2][CPB * 7 * AW_];   // [wave][ch_local*98 + row*14 + aw]

    // --- XCD-aware swizzle (identical to v0/v2) ---
    const int p   = blockIdx.x;
    const int xcd = p & 7;
    const int q   = p >> 3;
    const int n   = q & 255;           // roi index (advances fastest)
    const int cgi = q >> 8;            // 0..7
    const int cg  = cgi * 8 + xcd;     // 0..63
    const int c0  = cg * CPB;

    const int tid  = threadIdx.x;
    const int wave = tid >> 6;
    const int lane = tid & 63;
    const int half = lane >> 5;        // channel within a pair
    const int ix   = lane & 31;        // sample-x index (0..29 used)

    // --- per-roi geometry (block-uniform; fp op order preserved) ---
    const float r0f = rois[n * 5 + 0];
    const float x1s = rois[n * 5 + 1] * 0.25f;
    const float y1s = rois[n * 5 + 2] * 0.25f;
    const float x2s = rois[n * 5 + 3] * 0.25f;
    const float y2s = rois[n * 5 + 4] * 0.25f;
    const int   b   = (int)r0f;

    const float cx = 0.5f * (x1s + x2s), cy = 0.5f * (y1s + y2s);
    const float hw = 0.5f * (x2s - x1s), hh = 0.5f * (y2s - y1s);
    const float x1 = cx - hw, x2 = cx + hw;
    const float y1 = cy - hh, y2 = cy + hh;
    const float roi_w = fmaxf(x2 - x1, 1.0f);
    const float roi_h = fmaxf(y2 - y1, 1.0f);
    const float sub_w = roi_w * (1.0f / 15.0f) * 0.5f;
    const float sub_h = roi_h * (1.0f / 15.0f) * 0.5f;

    // --- x-direction sample metadata: per lane, computed once ---
    const float sx  = x1 + ((float)ix + 0.5f) * sub_w;
    const bool  vx_ = (sx > -1.0f) && (sx < (float)W_) && (ix < 30);
    const float ccx = fminf(fmaxf(sx, 0.0f), (float)(W_ - 1));
    const float lox = floorf(ccx);
    const int   xl  = (int)lox;
    const int   xh  = min(xl + 1, W_ - 1);
    const float fx  = ccx - lox;
    const float vmx = vx_ ? 1.0f : 0.0f;
    const float wx0 = (1.0f - fx) * vmx;
    const float wx1 = fx * vmx;

    // --- channel bases (block-uniform saddr) + hoisted per-lane offsets ---
    const float* __restrict__ bpA = feat + ((size_t)b * C_ + c0) * (size_t)HW_;
    const float* __restrict__ bpB = bpA + 2 * HW_;
    const int vx0 = half * HW_ + xl;   // channel-half + xl
    const int vx1 = half * HW_ + xh;

    const int  aw   = ix >> 1;
    const bool emit = ((lane & 1) == 0) && (aw < AW_);
    float* __restrict__ Lw = Ls[wave];

    // row-register state (4 corners per channel-pair) + scalar row tracking
    float alo0 = 0.f, alo1 = 0.f, ahi0 = 0.f, ahi1 = 0.f;
    float blo0 = 0.f, blo1 = 0.f, bhi0 = 0.f, bhi1 = 0.f;
    int   pyl = -100, pyh = -100;

    const int iy0 = wave * 14;         // wave0: iy 0..15, wave1: iy 14..29
    float prevSA = 0.f, prevSB = 0.f;

    for (int kk = 0; kk < 8; ++kk) {
        float PA = 0.f, PB = 0.f;
        #pragma unroll
        for (int r = 0; r < 2; ++r) {
            const int iy = iy0 + 2 * kk + r;
            // y geometry: wave-uniform
            const float sy  = y1 + ((float)iy + 0.5f) * sub_h;
            const bool  vy_ = (sy > -1.0f) && (sy < (float)H_);
            const float ccy = fminf(fmaxf(sy, 0.0f), (float)(H_ - 1));
            const float loy = floorf(ccy);
            const float fy  = ccy - loy;
            const float vmy = vy_ ? 1.0f : 0.0f;
            const float wy0 = (1.0f - fy) * vmy;
            const float wy1 = fy * vmy;

            const int yl_s = __builtin_amdgcn_readfirstlane((int)loy);
            const int yh_s = min(yl_s + 1, H_ - 1);

            if (yl_s == pyl && yh_s == pyh) {
                // full reuse: no loads this row
            } else if (yl_s == pyh) {
                // shift: previous hi row becomes lo; load only the new hi row
                alo0 = ahi0; alo1 = ahi1; blo0 = bhi0; blo1 = bhi1;
                const float* __restrict__ pa = bpA + yh_s * W_;
                const float* __restrict__ pb = bpB + yh_s * W_;
                ahi0 = pa[vx0]; ahi1 = pa[vx1];
                bhi0 = pb[vx0]; bhi1 = pb[vx1];
            } else {
                const float* __restrict__ pal = bpA + yl_s * W_;
                const float* __restrict__ pah = bpA + yh_s * W_;
                const float* __restrict__ pbl = bpB + yl_s * W_;
                const float* __restrict__ pbh = bpB + yh_s * W_;
                alo0 = pal[vx0]; alo1 = pal[vx1];
                ahi0 = pah[vx0]; ahi1 = pah[vx1];
                blo0 = pbl[vx0]; blo1 = pbl[vx1];
                bhi0 = pbh[vx0]; bhi1 = pbh[vx1];
            }
            pyl = yl_s; pyh = yh_s;

            const float w00 = wy0 * wx0, w01 = wy0 * wx1;
            const float w10 = wy1 * wx0, w11 = wy1 * wx1;
            PA += alo0 * w00 + alo1 * w01 + ahi0 * w10 + ahi1 * w11;
            PB += blo0 * w00 + blo1 * w01 + bhi0 * w10 + bhi1 * w11;
        }
        // horizontal pooling in registers (per channel-pair)
        const float tA = PA + __shfl_xor(PA, 1, 64);
        const float uA = tA + __shfl_down(tA, 2, 64);
        const float tB = PB + __shfl_xor(PB, 1, 64);
        const float uB = tB + __shfl_down(tB, 2, 64);
        if (kk > 0 && emit) {
            const int row = kk - 1;                    // 0..6 within this wave
            Lw[half * 98 + row * AW_ + aw]       = (prevSA + uA) * 0.0625f;
            Lw[(2 + half) * 98 + row * AW_ + aw] = (prevSB + uB) * 0.0625f;
        }
        prevSA = uA;
        prevSB = uB;
    }

    // --- coalesced writeback: wave w writes rows [7w, 7w+7) of 4 channels ---
    float* __restrict__ op = out + ((size_t)n * C_ + c0) * (AH_ * AW_);
    for (int o = lane; o < CPB * 7 * AW_; o += 64) {   // 392 floats
        const int ch  = o / 98;                        // magic-mul div
        const int rem = o - ch * 98;
        op[ch * (AH_ * AW_) + wave * 98 + rem] = Lw[o];
    }
}

extern "C" void kernel_launch(void* const* d_in, const int* in_sizes, int n_in,
                              void* d_out, int out_size, void* d_ws, size_t ws_size,
                              hipStream_t stream) {
    const float* feat = (const float*)d_in[0];
    const float* rois = (const float*)d_in[1];
    float* out = (float*)d_out;
    const int grid = 256 * (C_ / CPB);   // 16384 blocks, 128 threads
    roi_mask_align_avg_kernel<<<grid, 128, 0, stream>>>(feat, rois, out);
}

// Round 4
// 233.496 us; speedup vs baseline: 1.2249x; 1.0512x over previous
//
#include <hip/hip_runtime.h>

// RoIMaskAlignAvg: features (B=2, C=256, H=200, W=272) fp32, rois (N=256,5)
// -> out (N, C, 14, 14) fp32.
//
// v4: replace scattered per-lane corner gathers (4 global_load_dword x 64
// data-dependent addrs per new feature row -> TA address wall) with
// COOPERATIVE SPAN STAGING:
//  - all corners of a feature row lie in a <=128-col window
//    (29*sub_w <= 103 by roi-size bound, +24 margin);
//    window start s0c = min(s0, W-128) keeps it in-row and covering.
//  - stage the window for 4 channels with 2 global_load_lds_dwordx4
//    (lanes 0-31 -> channel-half 0, lanes 32-63 -> half 1; coalesced 512B
//    bursts; tail lanes masked off -- unread slots never consumed).
//  - corners via ds_read2_b32 at LOOP-INVARIANT per-lane offset (xl - s0c).
//  - VMEM instrs halve (2/row vs 4/row); address work moves to LDS pipe.
// Kept from v3: XCD swizzle (L2 slice), scalar-branch row reuse, register
// shuffle pooling, LDS output staging + coalesced writeback.
//
// Wave LDS buffer layout (floats):
//   [0,256)     rowbuf LO, pair A   (half h at h*128, col c at (c-s0c))
//   [256,512)   rowbuf LO, pair B
//   [512,768)   rowbuf HI, pair A
//   [768,1024)  rowbuf HI, pair B
//   [1024]      pad, zeroed (clamp-overflow read target, weight always 0)
//   [1028,1420) output staging (392 floats)

#define AH_  14
#define AW_  14
#define C_   256
#define H_   200
#define W_   272
#define HW_  (H_ * W_)
#define CPB  4
#define WBUF 1424

#define GLOAD_LDS16(g, l)                                                     \
  __builtin_amdgcn_global_load_lds(                                           \
      (const __attribute__((address_space(1))) void*)(g),                     \
      (__attribute__((address_space(3))) void*)(l), 16, 0, 0)

__global__ __launch_bounds__(128)
void roi_mask_align_avg_kernel(const float* __restrict__ feat,
                               const float* __restrict__ rois,
                               float* __restrict__ out) {
    __shared__ float Ls[2][WBUF];   // 11392 B/block

    // --- XCD-aware swizzle (identical to v0/v2/v3) ---
    const int p   = blockIdx.x;
    const int xcd = p & 7;
    const int q   = p >> 3;
    const int n   = q & 255;           // roi index (advances fastest)
    const int cgi = q >> 8;            // 0..7
    const int cg  = cgi * 8 + xcd;     // 0..63
    const int c0  = cg * CPB;

    const int tid  = threadIdx.x;
    const int wave = tid >> 6;
    const int lane = tid & 63;
    const int half = lane >> 5;        // channel within a pair
    const int ix   = lane & 31;        // sample-x index (0..29 used)

    float* __restrict__ LsW = Ls[wave];
    if (lane == 0) LsW[1024] = 0.0f;   // pad slot (same-wave use, no barrier)

    // --- per-roi geometry (block-uniform; fp op order preserved) ---
    const float r0f = rois[n * 5 + 0];
    const float x1s = rois[n * 5 + 1] * 0.25f;
    const float y1s = rois[n * 5 + 2] * 0.25f;
    const float x2s = rois[n * 5 + 3] * 0.25f;
    const float y2s = rois[n * 5 + 4] * 0.25f;
    const int   b   = (int)r0f;

    const float cx = 0.5f * (x1s + x2s), cy = 0.5f * (y1s + y2s);
    const float hw = 0.5f * (x2s - x1s), hh = 0.5f * (y2s - y1s);
    const float x1 = cx - hw, x2 = cx + hw;
    const float y1 = cy - hh, y2 = cy + hh;
    const float roi_w = fmaxf(x2 - x1, 1.0f);
    const float roi_h = fmaxf(y2 - y1, 1.0f);
    const float sub_w = roi_w * (1.0f / 15.0f) * 0.5f;
    const float sub_h = roi_h * (1.0f / 15.0f) * 0.5f;

    // --- x-direction sample metadata: per lane, computed once ---
    const float sx  = x1 + ((float)ix + 0.5f) * sub_w;
    const bool  vx_ = (sx > -1.0f) && (sx < (float)W_) && (ix < 30);
    const float ccx = fminf(fmaxf(sx, 0.0f), (float)(W_ - 1));
    const float lox = floorf(ccx);
    const int   xl  = (int)lox;
    const int   xh  = min(xl + 1, W_ - 1);
    const float fx  = ccx - lox;
    const float vmx = vx_ ? 1.0f : 0.0f;
    const float wx0 = (1.0f - fx) * vmx;
    const float wx1 = fx * vmx;

    // --- span window (scalar) + loop-invariant per-lane offsets ---
    const int s0    = __builtin_amdgcn_readfirstlane(xl);   // = xl at ix=0
    const int s0c   = min(s0, W_ - 128);                    // window start
    const int xh29  = __builtin_amdgcn_readlane(xh, 29);    // max needed col
    const int spanrel = xh29 - s0c;                         // <= 127 (proven)
    const bool ldact  = (ix * 4) <= spanrel;                // staging mask
    const int iA    = half * 128 + (xl - s0c);              // read idx in block

    // per-lane global base pointers for staging (row 0, own 4-col chunk)
    const float* __restrict__ bpA = feat + ((size_t)b * C_ + c0) * (size_t)HW_;
    const float* __restrict__ gA  = bpA + (size_t)half * HW_ + s0c + 4 * ix;
    const float* __restrict__ gB  = gA + 2 * HW_;

    const int  aw   = ix >> 1;
    const bool emit = ((lane & 1) == 0) && (aw < AW_);
    float* __restrict__ Ow = LsW + 1028;   // output staging

    // row-register state (4 corners per channel-pair) + scalar row tracking
    float alo0 = 0.f, alo1 = 0.f, ahi0 = 0.f, ahi1 = 0.f;
    float blo0 = 0.f, blo1 = 0.f, bhi0 = 0.f, bhi1 = 0.f;
    int   pyl = -100, pyh = -100;

    const int iy0 = wave * 14;         // wave0: iy 0..15, wave1: iy 14..29
    float prevSA = 0.f, prevSB = 0.f;

    for (int kk = 0; kk < 8; ++kk) {
        float PA = 0.f, PB = 0.f;
        #pragma unroll
        for (int r = 0; r < 2; ++r) {
            const int iy = iy0 + 2 * kk + r;
            // y geometry: wave-uniform
            const float sy  = y1 + ((float)iy + 0.5f) * sub_h;
            const bool  vy_ = (sy > -1.0f) && (sy < (float)H_);
            const float ccy = fminf(fmaxf(sy, 0.0f), (float)(H_ - 1));
            const float loy = floorf(ccy);
            const float fy  = ccy - loy;
            const float vmy = vy_ ? 1.0f : 0.0f;
            const float wy0 = (1.0f - fy) * vmy;
            const float wy1 = fy * vmy;

            const int yl_s = __builtin_amdgcn_readfirstlane((int)loy);
            const int yh_s = min(yl_s + 1, H_ - 1);

            if (yl_s == pyl && yh_s == pyh) {
                // full reuse: no memory traffic this row
            } else if (yl_s == pyh) {
                // shift: prev hi row -> lo (registers); stage only new hi row
                alo0 = ahi0; alo1 = ahi1; blo0 = bhi0; blo1 = bhi1;
                const int ro = yh_s * W_;
                asm volatile("s_waitcnt lgkmcnt(0)" ::: "memory");
                if (ldact) {
                    GLOAD_LDS16(gA + ro, LsW + 512);
                    GLOAD_LDS16(gB + ro, LsW + 768);
                }
                asm volatile("s_waitcnt vmcnt(0)" ::: "memory");
                ahi0 = LsW[512 + iA]; ahi1 = LsW[512 + iA + 1];
                bhi0 = LsW[768 + iA]; bhi1 = LsW[768 + iA + 1];
            } else {
                // stage both rows
                const int rlo = yl_s * W_, rhi = yh_s * W_;
                asm volatile("s_waitcnt lgkmcnt(0)" ::: "memory");
                if (ldact) {
                    GLOAD_LDS16(gA + rlo, LsW + 0);
                    GLOAD_LDS16(gB + rlo, LsW + 256);
                    GLOAD_LDS16(gA + rhi, LsW + 512);
                    GLOAD_LDS16(gB + rhi, LsW + 768);
                }
                asm volatile("s_waitcnt vmcnt(0)" ::: "memory");
                alo0 = LsW[iA];       alo1 = LsW[iA + 1];
                blo0 = LsW[256 + iA]; blo1 = LsW[256 + iA + 1];
                ahi0 = LsW[512 + iA]; ahi1 = LsW[512 + iA + 1];
                bhi0 = LsW[768 + iA]; bhi1 = LsW[768 + iA + 1];
            }
            pyl = yl_s; pyh = yh_s;

            const float w00 = wy0 * wx0, w01 = wy0 * wx1;
            const float w10 = wy1 * wx0, w11 = wy1 * wx1;
            PA += alo0 * w00 + alo1 * w01 + ahi0 * w10 + ahi1 * w11;
            PB += blo0 * w00 + blo1 * w01 + bhi0 * w10 + bhi1 * w11;
        }
        // horizontal pooling in registers (per channel-pair)
        const float tA = PA + __shfl_xor(PA, 1, 64);
        const float uA = tA + __shfl_down(tA, 2, 64);
        const float tB = PB + __shfl_xor(PB, 1, 64);
        const float uB = tB + __shfl_down(tB, 2, 64);
        if (kk > 0 && emit) {
            const int row = kk - 1;                    // 0..6 within this wave
            Ow[half * 98 + row * AW_ + aw]       = (prevSA + uA) * 0.0625f;
            Ow[(2 + half) * 98 + row * AW_ + aw] = (prevSB + uB) * 0.0625f;
        }
        prevSA = uA;
        prevSB = uB;
    }

    // --- coalesced writeback: wave w writes rows [7w, 7w+7) of 4 channels ---
    float* __restrict__ op = out + ((size_t)n * C_ + c0) * (AH_ * AW_);
    for (int o = lane; o < CPB * 7 * AW_; o += 64) {   // 392 floats
        const int ch  = o / 98;
        const int rem = o - ch * 98;
        op[ch * (AH_ * AW_) + wave * 98 + rem] = Ow[o];
    }
}

extern "C" void kernel_launch(void* const* d_in, const int* in_sizes, int n_in,
                              void* d_out, int out_size, void* d_ws, size_t ws_size,
                              hipStream_t stream) {
    const float* feat = (const float*)d_in[0];
    const float* rois = (const float*)d_in[1];
    float* out = (float*)d_out;
    const int grid = 256 * (C_ / CPB);   // 16384 blocks, 128 threads
    roi_mask_align_avg_kernel<<<grid, 128, 0, stream>>>(feat, rois, out);
}